// Round 4
// baseline (499.068 us; speedup 1.0000x reference)
//
#include <hip/hip_runtime.h>

#define NRAD  6
#define HID   128
#define VOCAB 95
#define EPB   128   // edges per block (main kernel)

__device__ __forceinline__ float swishf(float v) {
    // v * sigmoid(v) = v / (1 + exp(-v)); v_exp + v_rcp, ~1ulp each
    return v * __builtin_amdgcn_rcpf(1.0f + __expf(-v));
}

// ---------------------------------------------------------------------------
// Kernel A: precompute (tiny: ~6 MFLOP)
//   A1[v][c] = dot(emb[v], W_lin[c, 0:128])   + b_lin[c]
//   A2[v][c] = dot(emb[v], W_lin[c, 128:256])
//   W3T[k][c] = W_lin[c][256+k]   (transposed: k-major for the edge GEMM)
// ---------------------------------------------------------------------------
__global__ void precompute_kernel(const float* __restrict__ emb,   // [95][128]
                                  const float* __restrict__ Wl,    // [128][384]
                                  const float* __restrict__ bl,    // [128]
                                  float* __restrict__ A1,
                                  float* __restrict__ A2,
                                  float* __restrict__ W3T)
{
    const int blk = blockIdx.x;
    const int t = threadIdx.x;   // 128 threads
    if (blk < VOCAB) {
        __shared__ __align__(16) float se[HID];
        se[t] = emb[blk * HID + t];
        __syncthreads();
        float s1 = bl[t];
        float s2 = 0.0f;
        const float4* w1 = reinterpret_cast<const float4*>(Wl + t * 384);
        const float4* w2 = reinterpret_cast<const float4*>(Wl + t * 384 + 128);
        #pragma unroll
        for (int d4 = 0; d4 < 32; ++d4) {
            float4 a = w1[d4];
            float4 b = w2[d4];
            float e0 = se[d4*4+0], e1 = se[d4*4+1], e2 = se[d4*4+2], e3 = se[d4*4+3];
            s1 += e0*a.x + e1*a.y + e2*a.z + e3*a.w;
            s2 += e0*b.x + e1*b.y + e2*b.z + e3*b.w;
        }
        A1[blk * HID + t] = s1;
        A2[blk * HID + t] = s2;
    } else {
        // block VOCAB: transpose W3 = W_lin[:, 256:384] (tiny, once)
        for (int k = 0; k < HID; ++k)
            W3T[k * HID + t] = Wl[t * 384 + 256 + k];
    }
}

// ---------------------------------------------------------------------------
// Kernel B: main fused kernel. Per block: 128 edges, 256 threads.
//   Phase 1: rbf_h[e][k] = swish(rbf[e] . W_rbf[k] + b_rbf[k]) -> LDS [k][e]
//   Phase 2: acc[e][c] = sum_k rbf_h[k][e] * W3T[k][c]   (8x8 micro-tile,
//            W3T streamed from global: 64 KB shared by all blocks -> L2-hot)
//   Phase 3: out[e][c] = swish(acc + A1[x[i[e]]][c] + A2[x[j[e]]][c])
// ---------------------------------------------------------------------------
__global__ __launch_bounds__(256, 2) void main_kernel(
    const int*   __restrict__ xidx,   // [N_NODES]
    const float* __restrict__ rbf,    // [E][6]
    const int*   __restrict__ ei,     // [E]
    const int*   __restrict__ ej,     // [E]
    const float* __restrict__ Wr,     // [128][6]
    const float* __restrict__ br,     // [128]
    const float* __restrict__ A1,     // [95][128]  (b_lin folded in)
    const float* __restrict__ A2,     // [95][128]
    const float* __restrict__ W3T,    // [128][128]
    float*       __restrict__ out,    // [E][128]
    int E)
{
    __shared__ __align__(16) float sh_h[HID][EPB];   // 64 KB, [k][e]
    __shared__ float sh_wr[HID * 7];                 // W_rbf rows + b_rbf

    const int tid = threadIdx.x;
    const long eb = (long)blockIdx.x * EPB;

    // stage W_rbf (row-major, stride 7: 6 weights + bias)
    if (tid < HID) {
        #pragma unroll
        for (int r = 0; r < NRAD; ++r) sh_wr[tid * 7 + r] = Wr[tid * NRAD + r];
        sh_wr[tid * 7 + 6] = br[tid];
    }

    // ---- phase 1: rbf_h into LDS (transposed [k][e]) ----
    {
        const int el = tid & (EPB - 1);
        const int kg = tid >> 7;              // 0..1 -> k range [kg*64, kg*64+64)
        const long e = eb + el;
        float r0 = 0, r1 = 0, r2 = 0, r3 = 0, r4 = 0, r5 = 0;
        if (e < E) {
            const float* rp = rbf + e * NRAD;
            r0 = rp[0]; r1 = rp[1]; r2 = rp[2]; r3 = rp[3]; r4 = rp[4]; r5 = rp[5];
        }
        __syncthreads();   // sh_wr ready
        #pragma unroll 4
        for (int kk = 0; kk < 64; ++kk) {
            const int k = kg * 64 + kk;
            const float* w = &sh_wr[k * 7];
            float m = w[6] + r0*w[0] + r1*w[1] + r2*w[2] + r3*w[3] + r4*w[4] + r5*w[5];
            sh_h[k][el] = swishf(m);          // consecutive lanes -> conflict-free
        }
    }
    __syncthreads();

    // ---- phase 2: GEMM, 8 edges x 8 channels per thread, 2-deep pipeline ----
    const int tc = tid & 15;       // 16 channel groups
    const int te = tid >> 4;       // 16 edge groups
    const int c0 = tc * 8;
    const int e0 = te * 8;

    float acc[8][8];
    #pragma unroll
    for (int a = 0; a < 8; ++a)
        #pragma unroll
        for (int b = 0; b < 8; ++b) acc[a][b] = 0.0f;

    // prefetch k=0 weights
    float4 nb0 = *reinterpret_cast<const float4*>(W3T + c0);
    float4 nb1 = *reinterpret_cast<const float4*>(W3T + c0 + 4);

    #pragma unroll 4
    for (int k = 0; k < HID; ++k) {
        float4 b0 = nb0, b1 = nb1;
        if (k + 1 < HID) {   // issue next-k weight loads early; FMAs cover latency
            nb0 = *reinterpret_cast<const float4*>(W3T + (k + 1) * HID + c0);
            nb1 = *reinterpret_cast<const float4*>(W3T + (k + 1) * HID + c0 + 4);
        }
        float4 a0 = *reinterpret_cast<const float4*>(&sh_h[k][e0]);      // broadcast
        float4 a1 = *reinterpret_cast<const float4*>(&sh_h[k][e0 + 4]);  // broadcast
        float av[8] = {a0.x, a0.y, a0.z, a0.w, a1.x, a1.y, a1.z, a1.w};
        float bv[8] = {b0.x, b0.y, b0.z, b0.w, b1.x, b1.y, b1.z, b1.w};
        #pragma unroll
        for (int a = 0; a < 8; ++a)
            #pragma unroll
            for (int b = 0; b < 8; ++b)
                acc[a][b] += av[a] * bv[b];
    }

    // ---- phase 3: epilogue (A1/A2 gather + swish + store) ----
    #pragma unroll
    for (int le = 0; le < 8; ++le) {
        const long e = eb + e0 + le;
        if (e < E) {
            const int xi = xidx[ei[e]];
            const int xj = xidx[ej[e]];
            const float4* p1 = reinterpret_cast<const float4*>(A1 + xi * HID + c0);
            const float4* p2 = reinterpret_cast<const float4*>(A2 + xj * HID + c0);
            float4 q1a = p1[0], q1b = p1[1];
            float4 q2a = p2[0], q2b = p2[1];
            float4 o0, o1;
            o0.x = swishf(acc[le][0] + q1a.x + q2a.x);
            o0.y = swishf(acc[le][1] + q1a.y + q2a.y);
            o0.z = swishf(acc[le][2] + q1a.z + q2a.z);
            o0.w = swishf(acc[le][3] + q1a.w + q2a.w);
            o1.x = swishf(acc[le][4] + q1b.x + q2b.x);
            o1.y = swishf(acc[le][5] + q1b.y + q2b.y);
            o1.z = swishf(acc[le][6] + q1b.z + q2b.z);
            o1.w = swishf(acc[le][7] + q1b.w + q2b.w);
            *reinterpret_cast<float4*>(out + e * HID + c0)     = o0;
            *reinterpret_cast<float4*>(out + e * HID + c0 + 4) = o1;
        }
    }
}

extern "C" void kernel_launch(void* const* d_in, const int* in_sizes, int n_in,
                              void* d_out, int out_size, void* d_ws, size_t ws_size,
                              hipStream_t stream) {
    const int*   x   = (const int*)  d_in[0];
    const float* rbf = (const float*)d_in[1];
    const int*   ei  = (const int*)  d_in[2];
    const int*   ej  = (const int*)  d_in[3];
    const float* emb = (const float*)d_in[4];
    const float* Wr  = (const float*)d_in[5];
    const float* br  = (const float*)d_in[6];
    const float* Wl  = (const float*)d_in[7];
    const float* bl  = (const float*)d_in[8];
    float* out = (float*)d_out;

    const int E = in_sizes[1] / NRAD;   // 500000

    float* A1  = (float*)d_ws;                 // [95][128]
    float* A2  = A1 + VOCAB * HID;             // [95][128]
    float* W3T = A2 + VOCAB * HID;             // [128][128]

    precompute_kernel<<<VOCAB + 1, HID, 0, stream>>>(emb, Wl, bl, A1, A2, W3T);

    const int nblk = (E + EPB - 1) / EPB;
    main_kernel<<<nblk, 256, 0, stream>>>(x, rbf, ei, ej, Wr, br, A1, A2, W3T, out, E);
}

// Round 5
// 408.288 us; speedup vs baseline: 1.2223x; 1.2223x over previous
//
#include <hip/hip_runtime.h>
#include <hip/hip_bf16.h>

#define NRAD  6
#define HID   128
#define VOCAB 95
#define EPB   128   // edges per block tile

typedef __attribute__((ext_vector_type(4))) float f32x4;
typedef __attribute__((ext_vector_type(8))) short short8;

__device__ __forceinline__ float swishf(float v) {
    return v * __builtin_amdgcn_rcpf(1.0f + __expf(-v));
}

__device__ __forceinline__ unsigned short bfbits(float x) {
    __hip_bfloat16 b = __float2bfloat16(x);   // RNE
    unsigned short u;
    __builtin_memcpy(&u, &b, 2);
    return u;
}

// ---------------------------------------------------------------------------
// Precompute: A1[v][c] = emb[v]·W_lin[c,0:128] + b_lin[c]
//             A2[v][c] = emb[v]·W_lin[c,128:256]
//             W3bf[c][k] = bf16(W_lin[c][256+k])   (c-major, k contiguous)
// ---------------------------------------------------------------------------
__global__ void precompute_kernel(const float* __restrict__ emb,   // [95][128]
                                  const float* __restrict__ Wl,    // [128][384]
                                  const float* __restrict__ bl,    // [128]
                                  float* __restrict__ A1,
                                  float* __restrict__ A2,
                                  unsigned short* __restrict__ W3bf)
{
    const int blk = blockIdx.x;
    const int t = threadIdx.x;   // 128 threads
    if (blk < VOCAB) {
        __shared__ __align__(16) float se[HID];
        se[t] = emb[blk * HID + t];
        __syncthreads();
        float s1 = bl[t];
        float s2 = 0.0f;
        const float4* w1 = reinterpret_cast<const float4*>(Wl + t * 384);
        const float4* w2 = reinterpret_cast<const float4*>(Wl + t * 384 + 128);
        #pragma unroll
        for (int d4 = 0; d4 < 32; ++d4) {
            float4 a = w1[d4];
            float4 b = w2[d4];
            float e0 = se[d4*4+0], e1 = se[d4*4+1], e2 = se[d4*4+2], e3 = se[d4*4+3];
            s1 += e0*a.x + e1*a.y + e2*a.z + e3*a.w;
            s2 += e0*b.x + e1*b.y + e2*b.z + e3*b.w;
        }
        A1[blk * HID + t] = s1;
        A2[blk * HID + t] = s2;
    } else {
        // pack W3 -> bf16, row-major [c][k]
        #pragma unroll 4
        for (int k4 = 0; k4 < 32; ++k4) {
            const float4 v = *reinterpret_cast<const float4*>(Wl + t * 384 + 256 + k4 * 4);
            uint2 pr;
            pr.x = (unsigned)bfbits(v.x) | ((unsigned)bfbits(v.y) << 16);
            pr.y = (unsigned)bfbits(v.z) | ((unsigned)bfbits(v.w) << 16);
            *reinterpret_cast<uint2*>(W3bf + t * HID + k4 * 4) = pr;
        }
    }
}

// ---------------------------------------------------------------------------
// Main kernel: 128 edges x 128 ch per block, 4 waves (2 edge-halves x 2 ch-halves).
// Per wave: 64e x 64c via 16x16x32 bf16 MFMA; M_rep=4, N_rep=4, 4 K-steps.
//   A-frags (P = swish(rbf·Wr+br)) computed in-register in MFMA layout.
//   B-frags (W3bf) loaded once from global (L2-hot, 64 KB shared by all blocks).
// Epilogue: + A1[x[i]] + A2[x[j]] (fp32 exact), swish, store.
// ---------------------------------------------------------------------------
__global__ __launch_bounds__(256, 2) void main_kernel(
    const int*   __restrict__ xidx,   // [N_NODES]
    const float* __restrict__ rbf,    // [E][6]
    const int*   __restrict__ ei,     // [E]
    const int*   __restrict__ ej,     // [E]
    const float* __restrict__ Wr,     // [128][6]
    const float* __restrict__ br,     // [128]
    const float* __restrict__ A1,     // [95][128]
    const float* __restrict__ A2,     // [95][128]
    const unsigned short* __restrict__ W3bf, // [128][128] bf16, c-major
    float*       __restrict__ out,    // [E][128]
    int E)
{
    __shared__ __align__(16) float sh_rbf[EPB * 8];  // [e][8]: r0..r5,-,-   4 KB
    __shared__ __align__(16) float sh_wr[HID * 8];   // [k][8]: w0..w5,b,-   4 KB

    const int tid  = threadIdx.x;
    const int lane = tid & 63;
    const int wid  = tid >> 6;       // 0..3
    const int wrh  = wid >> 1;       // edge half
    const int wch  = wid & 1;        // channel half
    const int g    = lane >> 4;      // 0..3 (k-group / C-row-group)
    const int lm   = lane & 15;      // A row / B col / C col

    const long base = (long)blockIdx.x * EPB;

    // ---- B fragments: persistent, 64 VGPR ----
    short8 bfr[4][4];
    #pragma unroll
    for (int nf = 0; nf < 4; ++nf)
        #pragma unroll
        for (int kf = 0; kf < 4; ++kf) {
            const int c = wch * 64 + nf * 16 + lm;
            const int k = kf * 32 + g * 8;
            bfr[nf][kf] = *reinterpret_cast<const short8*>(W3bf + c * HID + k);
        }

    // ---- stage rbf tile + W_rbf/b_rbf into LDS (768 floats each, 3 iters) ----
    #pragma unroll
    for (int it = 0; it < 3; ++it) {
        const int idx = tid + it * 256;
        const long gi = base * NRAD + idx;
        const float v = (gi < (long)E * NRAD) ? rbf[gi] : 0.0f;
        sh_rbf[(idx / NRAD) * 8 + idx % NRAD] = v;
    }
    #pragma unroll
    for (int it = 0; it < 3; ++it) {
        const int idx = tid + it * 256;
        sh_wr[(idx / NRAD) * 8 + idx % NRAD] = Wr[idx];
    }
    if (tid < HID) sh_wr[tid * 8 + 6] = br[tid];
    __syncthreads();

    // ---- per-lane rbf registers: one edge row per M-group ----
    float rb[4][6];
    #pragma unroll
    for (int m = 0; m < 4; ++m) {
        const int el = wrh * 64 + m * 16 + lm;
        const float4 a = *reinterpret_cast<const float4*>(&sh_rbf[el * 8]);
        const float2 b = *reinterpret_cast<const float2*>(&sh_rbf[el * 8 + 4]);
        rb[m][0] = a.x; rb[m][1] = a.y; rb[m][2] = a.z;
        rb[m][3] = a.w; rb[m][4] = b.x; rb[m][5] = b.y;
    }

    f32x4 acc[4][4];
    #pragma unroll
    for (int m = 0; m < 4; ++m)
        #pragma unroll
        for (int nf = 0; nf < 4; ++nf)
            acc[m][nf] = (f32x4){0.f, 0.f, 0.f, 0.f};

    // ---- K loop: build A-frags in-register, 16 MFMA per step ----
    #pragma unroll
    for (int kf = 0; kf < 4; ++kf) {
        union { short8 v; unsigned u[4]; } afr[4];
        #pragma unroll
        for (int j2 = 0; j2 < 4; ++j2) {
            const int k0 = kf * 32 + g * 8 + j2 * 2;
            const float4 wa0 = *reinterpret_cast<const float4*>(&sh_wr[k0 * 8]);
            const float4 wb0 = *reinterpret_cast<const float4*>(&sh_wr[k0 * 8 + 4]);
            const float4 wa1 = *reinterpret_cast<const float4*>(&sh_wr[k0 * 8 + 8]);
            const float4 wb1 = *reinterpret_cast<const float4*>(&sh_wr[k0 * 8 + 12]);
            #pragma unroll
            for (int m = 0; m < 4; ++m) {
                float s0 = wb0.z;
                s0 = fmaf(rb[m][0], wa0.x, s0); s0 = fmaf(rb[m][1], wa0.y, s0);
                s0 = fmaf(rb[m][2], wa0.z, s0); s0 = fmaf(rb[m][3], wa0.w, s0);
                s0 = fmaf(rb[m][4], wb0.x, s0); s0 = fmaf(rb[m][5], wb0.y, s0);
                float s1 = wb1.z;
                s1 = fmaf(rb[m][0], wa1.x, s1); s1 = fmaf(rb[m][1], wa1.y, s1);
                s1 = fmaf(rb[m][2], wa1.z, s1); s1 = fmaf(rb[m][3], wa1.w, s1);
                s1 = fmaf(rb[m][4], wb1.x, s1); s1 = fmaf(rb[m][5], wb1.y, s1);
                const float p0 = swishf(s0);
                const float p1 = swishf(s1);
                afr[m].u[j2] = (unsigned)bfbits(p0) | ((unsigned)bfbits(p1) << 16);
            }
        }
        #pragma unroll
        for (int m = 0; m < 4; ++m)
            #pragma unroll
            for (int nf = 0; nf < 4; ++nf)
                acc[m][nf] = __builtin_amdgcn_mfma_f32_16x16x32_bf16(
                                 afr[m].v, bfr[nf][kf], acc[m][nf], 0, 0, 0);
    }

    // ---- epilogue: gathers (fp32 exact) + swish + store ----
    // C/D layout (m89-verified): col = lane&15, row = (lane>>4)*4 + reg
    #pragma unroll
    for (int m = 0; m < 4; ++m) {
        #pragma unroll
        for (int r = 0; r < 4; ++r) {
            const int el = wrh * 64 + m * 16 + g * 4 + r;
            const long e = base + el;
            if (e < E) {
                const int xi = xidx[ei[e]];
                const int xj = xidx[ej[e]];
                const float* p1 = A1 + xi * HID;
                const float* p2 = A2 + xj * HID;
                #pragma unroll
                for (int nf = 0; nf < 4; ++nf) {
                    const int c = wch * 64 + nf * 16 + lm;
                    const float v = acc[m][nf][r] + p1[c] + p2[c];
                    out[e * HID + c] = swishf(v);
                }
            }
        }
    }
}

extern "C" void kernel_launch(void* const* d_in, const int* in_sizes, int n_in,
                              void* d_out, int out_size, void* d_ws, size_t ws_size,
                              hipStream_t stream) {
    const int*   x   = (const int*)  d_in[0];
    const float* rbf = (const float*)d_in[1];
    const int*   ei  = (const int*)  d_in[2];
    const int*   ej  = (const int*)  d_in[3];
    const float* emb = (const float*)d_in[4];
    const float* Wr  = (const float*)d_in[5];
    const float* br  = (const float*)d_in[6];
    const float* Wl  = (const float*)d_in[7];
    const float* bl  = (const float*)d_in[8];
    float* out = (float*)d_out;

    const int E = in_sizes[1] / NRAD;   // 500000

    float* A1 = (float*)d_ws;                           // [95][128] f32
    float* A2 = A1 + VOCAB * HID;                       // [95][128] f32
    unsigned short* W3bf = (unsigned short*)(A2 + VOCAB * HID);  // [128][128] bf16

    precompute_kernel<<<VOCAB + 1, HID, 0, stream>>>(emb, Wl, bl, A1, A2, W3bf);

    const int nblk = (E + EPB - 1) / EPB;
    main_kernel<<<nblk, 256, 0, stream>>>(x, rbf, ei, ej, Wr, br, A1, A2, W3bf, out, E);
}